// Round 2
// baseline (410.318 us; speedup 1.0000x reference)
//
#include <hip/hip_runtime.h>
#include <hip/hip_bf16.h>

typedef unsigned short u16;
typedef unsigned int u32;
typedef __attribute__((ext_vector_type(8))) short short8;
typedef __attribute__((ext_vector_type(4))) float float4v;

#define T_DIM 2048
#define D_DIM 2048
#define N_DIM 11264
#define BD    5632
#define KE    256   // extra K from LoRA fold-in (L*R = 16*16)

__device__ __forceinline__ u16 f2bf(float f) {
    union { float f; u32 u; } v; v.f = f;
    u32 u = v.u;
    return (u16)((u + 0x7fffu + ((u >> 16) & 1u)) >> 16);  // RNE, inputs finite
}

__device__ __forceinline__ void gld16(const u16* g, u16* l) {
    // async global->LDS, 16B per lane; LDS dest = wave-uniform base + lane*16
    __builtin_amdgcn_global_load_lds((const __attribute__((address_space(1))) void*)g,
                                     (__attribute__((address_space(3))) void*)l, 16, 0, 0);
}

// ---------------------------------------------------------------------------
// Prep kernel (f32 inputs):
//  bid [0,11264):        W f32 -> Wb bf16 (2048 elems/block)
//  bid [11264,13312):    X f32 -> Xb bf16 (2048 elems/block)
//  bid [13312,15360):    per-token xa[t] = x[t,:].A[l_t]  (f32), scatter to
//                        dense xahat0/xahat1 (T x 256, bf16)
//  bid [15360,18176):    transpose B (256 x 11264 f32) -> BT (11264 x 256 bf16)
// ---------------------------------------------------------------------------
__global__ __launch_bounds__(256) void prep_kernel(
    const float* __restrict__ Xf, const float* __restrict__ Wf,
    const float* __restrict__ Af, const float* __restrict__ Bf,
    const int* __restrict__ widx,
    u16* __restrict__ Wb, u16* __restrict__ Xb,
    u16* __restrict__ XH0, u16* __restrict__ XH1, u16* __restrict__ BT)
{
    const int bid = blockIdx.x;
    const int tid = threadIdx.x;
    if (bid < 11264) {
        const size_t i = (size_t)bid * 2048 + tid * 8;
        const float4* p = (const float4*)(Wf + i);
        float4 a = p[0], b = p[1];
        short8 o;
        o[0] = (short)f2bf(a.x); o[1] = (short)f2bf(a.y);
        o[2] = (short)f2bf(a.z); o[3] = (short)f2bf(a.w);
        o[4] = (short)f2bf(b.x); o[5] = (short)f2bf(b.y);
        o[6] = (short)f2bf(b.z); o[7] = (short)f2bf(b.w);
        *(short8*)(Wb + i) = o;
    } else if (bid < 13312) {
        const size_t i = (size_t)(bid - 11264) * 2048 + tid * 8;
        const float4* p = (const float4*)(Xf + i);
        float4 a = p[0], b = p[1];
        short8 o;
        o[0] = (short)f2bf(a.x); o[1] = (short)f2bf(a.y);
        o[2] = (short)f2bf(a.z); o[3] = (short)f2bf(a.w);
        o[4] = (short)f2bf(b.x); o[5] = (short)f2bf(b.y);
        o[6] = (short)f2bf(b.z); o[7] = (short)f2bf(b.w);
        *(short8*)(Xb + i) = o;
    } else if (bid < 15360) {
        const int t = bid - 13312;
        const int l = widx[t];
        float acc[32];
#pragma unroll
        for (int j = 0; j < 32; ++j) acc[j] = 0.0f;

        const float* xrow = Xf + (size_t)t * D_DIM + tid * 8;
        const float* arow = Af + (size_t)l * (D_DIM * 32) + (size_t)tid * 8 * 32;
        float4 xv0 = ((const float4*)xrow)[0];
        float4 xv1 = ((const float4*)xrow)[1];
        float xv[8] = {xv0.x, xv0.y, xv0.z, xv0.w, xv1.x, xv1.y, xv1.z, xv1.w};
#pragma unroll
        for (int dd = 0; dd < 8; ++dd) {
            const float xf = xv[dd];
            const float4* ap = (const float4*)(arow + dd * 32);
#pragma unroll
            for (int c = 0; c < 8; ++c) {
                float4 av = ap[c];
                acc[c * 4 + 0] += xf * av.x;
                acc[c * 4 + 1] += xf * av.y;
                acc[c * 4 + 2] += xf * av.z;
                acc[c * 4 + 3] += xf * av.w;
            }
        }
        // wave butterfly reduce (64 lanes)
#pragma unroll
        for (int off = 32; off > 0; off >>= 1) {
#pragma unroll
            for (int j = 0; j < 32; ++j) acc[j] += __shfl_xor(acc[j], off);
        }
        __shared__ float red[4][32];
        const int wave = tid >> 6, lane = tid & 63;
        if (lane == 0) {
#pragma unroll
            for (int j = 0; j < 32; ++j) red[wave][j] = acc[j];
        }
        __syncthreads();
        __shared__ float xa[32];
        if (tid < 32) xa[tid] = red[0][tid] + red[1][tid] + red[2][tid] + red[3][tid];
        __syncthreads();
        // scatter: k = tid (0..255); xahat_h[t, l'*16+r] = (l'==l) ? xa[h*16+r] : 0
        const int k = tid, kl = k >> 4, r = k & 15;
        const bool hit = (kl == l);
        XH0[(size_t)t * KE + k] = hit ? f2bf(xa[r]) : (u16)0;
        XH1[(size_t)t * KE + k] = hit ? f2bf(xa[16 + r]) : (u16)0;
    } else {
        // 32x32 tiled transpose + convert: BT[n,k] = bf16(B[k,n])
        const int b = bid - 15360;
        const int nb = b >> 3;   // 0..351
        const int kb = b & 7;    // 0..7
        const int tx = tid & 31, ty = tid >> 5;
        __shared__ u16 tile[32][33];
        const int n = nb * 32 + tx;
#pragma unroll
        for (int i = 0; i < 4; ++i) {
            const int kk = kb * 32 + ty + i * 8;
            tile[ty + i * 8][tx] = f2bf(Bf[(size_t)kk * N_DIM + n]);
        }
        __syncthreads();
        const int k2 = kb * 32 + tx;
#pragma unroll
        for (int i = 0; i < 4; ++i) {
            const int n2 = nb * 32 + ty + i * 8;
            BT[(size_t)n2 * KE + k2] = tile[tx][ty + i * 8];
        }
    }
}

// ---------------------------------------------------------------------------
// Main GEMM: out[m,n] = sum_k xb[m,k] wb[n,k]  (K=2048, bf16)
//                     + sum_k xahat_h[m,k] BT[n,k]  (K=256, h by n-half)
// 128x128 tile, 4 waves (2x2), each wave 4x4 frags of 16x16x32 bf16 MFMA.
// BK=32. global_load_lds staging with XOR-swizzled LDS chunk layout:
//   LDS chunk c (16B) within a 16-row/1KB group holds global chunk c^((c>>3)&7)
//   -> fragment ds_read_b128 spreads over all 8 bank-quads (2-way, free).
// Output f32.
// ---------------------------------------------------------------------------
__global__ __launch_bounds__(256, 2) void gemm_kernel(
    const u16* __restrict__ X, const u16* __restrict__ W,
    const u16* __restrict__ XH0, const u16* __restrict__ XH1,
    const u16* __restrict__ BT, float* __restrict__ OUT)
{
    __shared__ __align__(16) u16 lsA[128 * 32];
    __shared__ __align__(16) u16 lsB[128 * 32];

    const int tid  = threadIdx.x;
    const int lane = tid & 63;
    const int wave = tid >> 6;
    const int wm = wave >> 1, wn = wave & 1;
    const int q = lane >> 4, c16 = lane & 15;
    const int bn = blockIdx.x, bm = blockIdx.y;
    const int m0 = bm * 128, n0 = bn * 128;

    // staging: lane's LDS chunk = lane (within instr); global chunk = involution
    const int gchunk = lane ^ ((lane >> 3) & 7);
    const int srow = gchunk >> 2;  // row within 16-row instruction span
    const int skq  = gchunk & 3;   // 16B chunk within 64B row

    // fragment read: local chunk for (row=c16, kchunk=q) within its group
    const int gl = (c16 << 2) | q;
    const int cl = gl ^ ((gl >> 3) & 7);

    u16* ldsA0 = lsA + wave * 1024;  // 16 rows x 32 k = 1024B per gld16
    u16* ldsA1 = ldsA0 + 512;
    u16* ldsB0 = lsB + wave * 1024;
    u16* ldsB1 = ldsB0 + 512;

    const size_t arow = (size_t)(m0 + wave * 32 + srow);
    const size_t brow = (size_t)(n0 + wave * 32 + srow);
    const int aoff = skq * 8;

    const u16* pa0 = X + arow * D_DIM + aoff;
    const u16* pa1 = pa0 + 16 * D_DIM;
    const u16* pb0 = W + brow * D_DIM + aoff;
    const u16* pb1 = pb0 + 16 * D_DIM;

    float4v acc[4][4] = {};

    auto mma_step = [&]() {
        short8 af[4], bf[4];
#pragma unroll
        for (int i = 0; i < 4; ++i)
            af[i] = *(const short8*)(lsA + (((wm * 4 + i) * 64 + cl) << 3));
#pragma unroll
        for (int j = 0; j < 4; ++j)
            bf[j] = *(const short8*)(lsB + (((wn * 4 + j) * 64 + cl) << 3));
#pragma unroll
        for (int i = 0; i < 4; ++i)
#pragma unroll
            for (int j = 0; j < 4; ++j)
                acc[i][j] = __builtin_amdgcn_mfma_f32_16x16x32_bf16(af[i], bf[j], acc[i][j], 0, 0, 0);
    };

    for (int kt = 0; kt < 64; ++kt) {
        const int k0 = kt * 32;
        __syncthreads();
        gld16(pa0 + k0, ldsA0);
        gld16(pa1 + k0, ldsA1);
        gld16(pb0 + k0, ldsB0);
        gld16(pb1 + k0, ldsB1);
        __syncthreads();
        mma_step();
    }

    // LoRA extra-K: 8 iterations, half selected by n-block (tiles never straddle)
    const u16* xah = (n0 < BD) ? XH0 : XH1;
    const u16* ea0 = xah + arow * KE + aoff;
    const u16* ea1 = ea0 + 16 * KE;
    const u16* eb0 = BT + brow * KE + aoff;
    const u16* eb1 = eb0 + 16 * KE;
    for (int kt = 0; kt < 8; ++kt) {
        const int k0 = kt * 32;
        __syncthreads();
        gld16(ea0 + k0, ldsA0);
        gld16(ea1 + k0, ldsA1);
        gld16(eb0 + k0, ldsB0);
        gld16(eb1 + k0, ldsB1);
        __syncthreads();
        mma_step();
    }

    // epilogue: C/D layout col = lane&15, row = (lane>>4)*4 + reg
    const int crow = m0 + wm * 64 + q * 4;
    const int ccol = n0 + wn * 64 + c16;
#pragma unroll
    for (int i = 0; i < 4; ++i)
#pragma unroll
        for (int j = 0; j < 4; ++j) {
#pragma unroll
            for (int r = 0; r < 4; ++r)
                OUT[(size_t)(crow + i * 16 + r) * N_DIM + (ccol + j * 16)] = acc[i][j][r];
        }
}

extern "C" void kernel_launch(void* const* d_in, const int* in_sizes, int n_in,
                              void* d_out, int out_size, void* d_ws, size_t ws_size,
                              hipStream_t stream) {
    const float* Xf  = (const float*)d_in[0];   // (2048, 2048) f32
    const float* Wf  = (const float*)d_in[1];   // (11264, 2048) f32
    const float* Af  = (const float*)d_in[2];   // (16, 2048, 32) f32
    const float* Bf  = (const float*)d_in[3];   // (16, 16, 11264) f32
    const int* widx  = (const int*)d_in[4];     // (2048,) int32 (JAX x64 off)
    float* OUT = (float*)d_out;                 // (2048, 11264) f32

    u16* Wb  = (u16*)d_ws;                            // 11264x2048 bf16 (46.1 MB)
    u16* Xb  = Wb + (size_t)N_DIM * D_DIM;            // 2048x2048 bf16 (8.4 MB)
    u16* XH0 = Xb + (size_t)T_DIM * D_DIM;            // 2048x256 bf16 (1 MB)
    u16* XH1 = XH0 + (size_t)T_DIM * KE;              // 2048x256 bf16 (1 MB)
    u16* BT  = XH1 + (size_t)T_DIM * KE;              // 11264x256 bf16 (5.5 MB)

    prep_kernel<<<dim3(18176), dim3(256), 0, stream>>>(Xf, Wf, Af, Bf, widx,
                                                       Wb, Xb, XH0, XH1, BT);
    gemm_kernel<<<dim3(N_DIM / 128, T_DIM / 128), dim3(256), 0, stream>>>(
        Xb, Wb, XH0, XH1, BT, OUT);
}

// Round 3
// 340.545 us; speedup vs baseline: 1.2049x; 1.2049x over previous
//
#include <hip/hip_runtime.h>
#include <hip/hip_bf16.h>

typedef unsigned short u16;
typedef unsigned int u32;
typedef __attribute__((ext_vector_type(8))) short short8;
typedef __attribute__((ext_vector_type(4))) float float4v;

#define T_DIM 2048
#define D_DIM 2048
#define N_DIM 11264
#define BD    5632
#define KE    256   // extra K from LoRA fold-in (L*R = 16*16)

__device__ __forceinline__ u16 f2bf(float f) {
    union { float f; u32 u; } v; v.f = f;
    u32 u = v.u;
    return (u16)((u + 0x7fffu + ((u >> 16) & 1u)) >> 16);  // RNE, inputs finite
}

__device__ __forceinline__ void gld16(const u16* g, u16* l) {
    // async global->LDS, 16B per lane; LDS dest = wave-uniform base + lane*16
    __builtin_amdgcn_global_load_lds((const __attribute__((address_space(1))) void*)g,
                                     (__attribute__((address_space(3))) void*)l, 16, 0, 0);
}

// ---------------------------------------------------------------------------
// Prep kernel (f32 inputs), block ranges (latency-heavy parts first):
//  bid [0,2048):      xa[t] = x[t,:].A[l_t] (f32, coalesced wave loads),
//                     scatter to dense xahat0/xahat1 (T x 256 bf16)
//  bid [2048,4864):   transpose B (256 x 11264 f32) -> BT (11264 x 256 bf16)
//  bid [4864,5376):   X f32 -> Xb bf16 (32 elems/thread)
//  bid [5376,8192):   W f32 -> Wb bf16 (32 elems/thread)
// ---------------------------------------------------------------------------
__global__ __launch_bounds__(256) void prep_kernel(
    const float* __restrict__ Xf, const float* __restrict__ Wf,
    const float* __restrict__ Af, const float* __restrict__ Bf,
    const int* __restrict__ widx,
    u16* __restrict__ Wb, u16* __restrict__ Xb,
    u16* __restrict__ XH0, u16* __restrict__ XH1, u16* __restrict__ BT)
{
    const int bid = blockIdx.x;
    const int tid = threadIdx.x;

    __shared__ float lx[D_DIM];          // staged x row (8 KB)
    __shared__ float red[4][8][4];
    __shared__ float xa[32];
    __shared__ u16 tile[32][33];

    if (bid < 2048) {
        // ---- xa for token t ----
        const int t = bid;
        const int l = widx[t];
        const float4* xr = (const float4*)(Xf + (size_t)t * D_DIM);
        ((float4*)lx)[tid]       = xr[tid];
        ((float4*)lx)[tid + 256] = xr[tid + 256];
        __syncthreads();

        const int wave = tid >> 6, lane = tid & 63;
        const int rowg = lane >> 3, chunk = lane & 7;
        // wave-load: 8 consecutive rows x 128 B, fully coalesced 1 KB
        const float* abase = Af + (size_t)l * (D_DIM * 32) + chunk * 4;
        float accx = 0.f, accy = 0.f, accz = 0.f, accw = 0.f;
#pragma unroll 4
        for (int i = 0; i < 64; ++i) {
            const int row = wave * 512 + i * 8 + rowg;
            const float4 av = *(const float4*)(abase + (size_t)row * 32);
            const float xf = lx[row];
            accx += xf * av.x; accy += xf * av.y;
            accz += xf * av.z; accw += xf * av.w;
        }
        // reduce across the 8 rowgroups (xor 8/16/32)
#pragma unroll
        for (int off = 8; off <= 32; off <<= 1) {
            accx += __shfl_xor(accx, off);
            accy += __shfl_xor(accy, off);
            accz += __shfl_xor(accz, off);
            accw += __shfl_xor(accw, off);
        }
        if (rowg == 0) {
            red[wave][chunk][0] = accx; red[wave][chunk][1] = accy;
            red[wave][chunk][2] = accz; red[wave][chunk][3] = accw;
        }
        __syncthreads();
        if (tid < 32) {
            const int c = tid >> 2, j = tid & 3;
            xa[c * 4 + j] = red[0][c][j] + red[1][c][j] + red[2][c][j] + red[3][c][j];
        }
        __syncthreads();
        // scatter: k = tid; xahat_h[t, l'*16+r] = (l'==l) ? xa[h*16+r] : 0
        const int k = tid, kl = k >> 4, r = k & 15;
        const bool hit = (kl == l);
        XH0[(size_t)t * KE + k] = hit ? f2bf(xa[r])      : (u16)0;
        XH1[(size_t)t * KE + k] = hit ? f2bf(xa[16 + r]) : (u16)0;
    } else if (bid < 4864) {
        // ---- 32x32 tiled transpose + convert: BT[n,k] = bf16(B[k,n]) ----
        const int b = bid - 2048;
        const int nb = b >> 3;   // 0..351
        const int kb = b & 7;    // 0..7
        const int tx = tid & 31, ty = tid >> 5;
        const int n = nb * 32 + tx;
#pragma unroll
        for (int i = 0; i < 4; ++i) {
            const int kk = kb * 32 + ty + i * 8;
            tile[ty + i * 8][tx] = f2bf(Bf[(size_t)kk * N_DIM + n]);
        }
        __syncthreads();
        const int k2 = kb * 32 + tx;
#pragma unroll
        for (int i = 0; i < 4; ++i) {
            const int n2 = nb * 32 + ty + i * 8;
            BT[(size_t)n2 * KE + k2] = tile[tx][ty + i * 8];
        }
    } else if (bid < 5376) {
        // ---- X convert: 32 f32/thread ----
        const size_t base = ((size_t)(bid - 4864) * 256 + tid) * 32;
        const float4* p = (const float4*)(Xf + base);
        float4 v[8];
#pragma unroll
        for (int i = 0; i < 8; ++i) v[i] = p[i];
#pragma unroll
        for (int i = 0; i < 4; ++i) {
            short8 o;
            o[0] = (short)f2bf(v[2*i].x);   o[1] = (short)f2bf(v[2*i].y);
            o[2] = (short)f2bf(v[2*i].z);   o[3] = (short)f2bf(v[2*i].w);
            o[4] = (short)f2bf(v[2*i+1].x); o[5] = (short)f2bf(v[2*i+1].y);
            o[6] = (short)f2bf(v[2*i+1].z); o[7] = (short)f2bf(v[2*i+1].w);
            *(short8*)(Xb + base + i * 8) = o;
        }
    } else {
        // ---- W convert: 32 f32/thread ----
        const size_t base = ((size_t)(bid - 5376) * 256 + tid) * 32;
        const float4* p = (const float4*)(Wf + base);
        float4 v[8];
#pragma unroll
        for (int i = 0; i < 8; ++i) v[i] = p[i];
#pragma unroll
        for (int i = 0; i < 4; ++i) {
            short8 o;
            o[0] = (short)f2bf(v[2*i].x);   o[1] = (short)f2bf(v[2*i].y);
            o[2] = (short)f2bf(v[2*i].z);   o[3] = (short)f2bf(v[2*i].w);
            o[4] = (short)f2bf(v[2*i+1].x); o[5] = (short)f2bf(v[2*i+1].y);
            o[6] = (short)f2bf(v[2*i+1].z); o[7] = (short)f2bf(v[2*i+1].w);
            *(short8*)(Wb + base + i * 8) = o;
        }
    }
}

// ---------------------------------------------------------------------------
// Main GEMM: out[m,n] = sum_k xb[m,k] wb[n,k]  (K=2048, bf16)
//                     + sum_k xahat_h[m,k] BT[n,k]  (K=256, h by n-half)
// 128x128 tile, 4 waves (2x2), each wave 4x4 frags of 16x16x32 bf16 MFMA.
// BK=32. global_load_lds staging with XOR-swizzled LDS chunk layout:
//   LDS chunk c (16B) within a 16-row/1KB group holds global chunk c^((c>>3)&7)
//   -> fragment ds_read_b128 spreads over all 8 bank-quads (2-way, free).
// Output f32.
// ---------------------------------------------------------------------------
__global__ __launch_bounds__(256, 2) void gemm_kernel(
    const u16* __restrict__ X, const u16* __restrict__ W,
    const u16* __restrict__ XH0, const u16* __restrict__ XH1,
    const u16* __restrict__ BT, float* __restrict__ OUT)
{
    __shared__ __align__(16) u16 lsA[128 * 32];
    __shared__ __align__(16) u16 lsB[128 * 32];

    const int tid  = threadIdx.x;
    const int lane = tid & 63;
    const int wave = tid >> 6;
    const int wm = wave >> 1, wn = wave & 1;
    const int q = lane >> 4, c16 = lane & 15;
    const int bn = blockIdx.x, bm = blockIdx.y;
    const int m0 = bm * 128, n0 = bn * 128;

    // staging: lane's LDS chunk = lane (within instr); global chunk = involution
    const int gchunk = lane ^ ((lane >> 3) & 7);
    const int srow = gchunk >> 2;  // row within 16-row instruction span
    const int skq  = gchunk & 3;   // 16B chunk within 64B row

    // fragment read: local chunk for (row=c16, kchunk=q) within its group
    const int gl = (c16 << 2) | q;
    const int cl = gl ^ ((gl >> 3) & 7);

    u16* ldsA0 = lsA + wave * 1024;  // 16 rows x 32 k = 1024B per gld16
    u16* ldsA1 = ldsA0 + 512;
    u16* ldsB0 = lsB + wave * 1024;
    u16* ldsB1 = ldsB0 + 512;

    const size_t arow = (size_t)(m0 + wave * 32 + srow);
    const size_t brow = (size_t)(n0 + wave * 32 + srow);
    const int aoff = skq * 8;

    const u16* pa0 = X + arow * D_DIM + aoff;
    const u16* pa1 = pa0 + 16 * D_DIM;
    const u16* pb0 = W + brow * D_DIM + aoff;
    const u16* pb1 = pb0 + 16 * D_DIM;

    float4v acc[4][4] = {};

    auto mma_step = [&]() {
        short8 af[4], bf[4];
#pragma unroll
        for (int i = 0; i < 4; ++i)
            af[i] = *(const short8*)(lsA + (((wm * 4 + i) * 64 + cl) << 3));
#pragma unroll
        for (int j = 0; j < 4; ++j)
            bf[j] = *(const short8*)(lsB + (((wn * 4 + j) * 64 + cl) << 3));
#pragma unroll
        for (int i = 0; i < 4; ++i)
#pragma unroll
            for (int j = 0; j < 4; ++j)
                acc[i][j] = __builtin_amdgcn_mfma_f32_16x16x32_bf16(af[i], bf[j], acc[i][j], 0, 0, 0);
    };

    for (int kt = 0; kt < 64; ++kt) {
        const int k0 = kt * 32;
        __syncthreads();
        gld16(pa0 + k0, ldsA0);
        gld16(pa1 + k0, ldsA1);
        gld16(pb0 + k0, ldsB0);
        gld16(pb1 + k0, ldsB1);
        __syncthreads();
        mma_step();
    }

    // LoRA extra-K: 8 iterations, half selected by n-block (tiles never straddle)
    const u16* xah = (n0 < BD) ? XH0 : XH1;
    const u16* ea0 = xah + arow * KE + aoff;
    const u16* ea1 = ea0 + 16 * KE;
    const u16* eb0 = BT + brow * KE + aoff;
    const u16* eb1 = eb0 + 16 * KE;
    for (int kt = 0; kt < 8; ++kt) {
        const int k0 = kt * 32;
        __syncthreads();
        gld16(ea0 + k0, ldsA0);
        gld16(ea1 + k0, ldsA1);
        gld16(eb0 + k0, ldsB0);
        gld16(eb1 + k0, ldsB1);
        __syncthreads();
        mma_step();
    }

    // epilogue: C/D layout col = lane&15, row = (lane>>4)*4 + reg
    const int crow = m0 + wm * 64 + q * 4;
    const int ccol = n0 + wn * 64 + c16;
#pragma unroll
    for (int i = 0; i < 4; ++i)
#pragma unroll
        for (int j = 0; j < 4; ++j) {
#pragma unroll
            for (int r = 0; r < 4; ++r)
                OUT[(size_t)(crow + i * 16 + r) * N_DIM + (ccol + j * 16)] = acc[i][j][r];
        }
}

extern "C" void kernel_launch(void* const* d_in, const int* in_sizes, int n_in,
                              void* d_out, int out_size, void* d_ws, size_t ws_size,
                              hipStream_t stream) {
    const float* Xf  = (const float*)d_in[0];   // (2048, 2048) f32
    const float* Wf  = (const float*)d_in[1];   // (11264, 2048) f32
    const float* Af  = (const float*)d_in[2];   // (16, 2048, 32) f32
    const float* Bf  = (const float*)d_in[3];   // (16, 16, 11264) f32
    const int* widx  = (const int*)d_in[4];     // (2048,) int32 (JAX x64 off)
    float* OUT = (float*)d_out;                 // (2048, 11264) f32

    u16* Wb  = (u16*)d_ws;                            // 11264x2048 bf16 (46.1 MB)
    u16* Xb  = Wb + (size_t)N_DIM * D_DIM;            // 2048x2048 bf16 (8.4 MB)
    u16* XH0 = Xb + (size_t)T_DIM * D_DIM;            // 2048x256 bf16 (1 MB)
    u16* XH1 = XH0 + (size_t)T_DIM * KE;              // 2048x256 bf16 (1 MB)
    u16* BT  = XH1 + (size_t)T_DIM * KE;              // 11264x256 bf16 (5.5 MB)

    prep_kernel<<<dim3(8192), dim3(256), 0, stream>>>(Xf, Wf, Af, Bf, widx,
                                                      Wb, Xb, XH0, XH1, BT);
    gemm_kernel<<<dim3(N_DIM / 128, T_DIM / 128), dim3(256), 0, stream>>>(
        Xb, Wb, XH0, XH1, BT, OUT);
}